// Round 6
// baseline (157.218 us; speedup 1.0000x reference)
//
#include <hip/hip_runtime.h>
#include <hip/hip_bf16.h>
#include <math.h>

typedef __attribute__((ext_vector_type(8))) short short8;
typedef __attribute__((ext_vector_type(4))) float f32x4;
typedef unsigned short u16;

static __device__ __forceinline__ u16 f2bf(float f) {
  union { float f; unsigned u; } v; v.f = f;
  unsigned r = v.u + 0x7fffu + ((v.u >> 16) & 1u);
  return (u16)(r >> 16);
}

static __device__ __forceinline__ void gload_lds16(const void* g, void* l) {
  __builtin_amdgcn_global_load_lds(
      (const __attribute__((address_space(1))) void*)g,
      (__attribute__((address_space(3))) void*)l, 16, 0, 0);
}

// ---------------- fp32 -> bf16 convert (8 elems/thread) ----------------
__global__ __launch_bounds__(256) void cvt_bf16(const float* __restrict__ in,
                                                u16* __restrict__ out, int n) {
  int i = (blockIdx.x * 256 + threadIdx.x) * 8;
  if (i >= n) return;
  float4 a = *(const float4*)(in + i);
  float4 b = *(const float4*)(in + i + 4);
  uint4 pk;
  pk.x = f2bf(a.x) | ((unsigned)f2bf(a.y) << 16);
  pk.y = f2bf(a.z) | ((unsigned)f2bf(a.w) << 16);
  pk.z = f2bf(b.x) | ((unsigned)f2bf(b.y) << 16);
  pk.w = f2bf(b.z) | ((unsigned)f2bf(b.w) << 16);
  *(uint4*)(out + i) = pk;
}

// -------- transpose fp32 W[KD][ND] -> bf16 WT[ND][KD] (tiled 64x64) --------
template<int KD, int ND>
__global__ __launch_bounds__(256) void transpose_bf16(const float* __restrict__ W,
                                                      u16* __restrict__ WT) {
  __shared__ float tile[64][65];
  const int c0 = blockIdx.x * 64;
  const int k0 = blockIdx.y * 64;
  const int t = threadIdx.x;
  const int lr = t >> 2;
  const int lc = (t & 3) * 16;
  const float* src = W + (size_t)(k0 + lr) * ND + c0 + lc;
#pragma unroll
  for (int i = 0; i < 16; i += 4) {
    float4 v = *(const float4*)(src + i);
    tile[lr][lc + i] = v.x; tile[lr][lc + i + 1] = v.y;
    tile[lr][lc + i + 2] = v.z; tile[lr][lc + i + 3] = v.w;
  }
  __syncthreads();
  unsigned pk[8];
#pragma unroll
  for (int j = 0; j < 8; ++j) {
    u16 lo = f2bf(tile[lc + 2 * j][lr]);
    u16 hi = f2bf(tile[lc + 2 * j + 1][lr]);
    pk[j] = lo | ((unsigned)hi << 16);
  }
  u16* dst = WT + (size_t)(c0 + lr) * KD + k0 + lc;
  *(uint4*)(dst) = make_uint4(pk[0], pk[1], pk[2], pk[3]);
  *(uint4*)(dst + 8) = make_uint4(pk[4], pk[5], pk[6], pk[7]);
}

// -------- GEMM: C[M,N] = A[M,1024] * Bt[N,1024]^T + bias --------
// MODE 0: scatter to q/k (bf16 [bh][t][64]) and V TRANSPOSED ([bh][d][t]);
// MODE 1: fp32 out [M][NSIZE]
template<int NSIZE, int MODE>
__global__ __launch_bounds__(256) void gemm_bt(const u16* __restrict__ A,
                                               const u16* __restrict__ Bt,
                                               const float* __restrict__ bias,
                                               u16* __restrict__ qb,
                                               u16* __restrict__ kb,
                                               u16* __restrict__ vb,
                                               float* __restrict__ outp) {
  constexpr int K = 1024;
  __shared__ u16 As[128 * 64];
  __shared__ u16 Bs[128 * 64];
  const int tid = threadIdx.x;
  const int lane = tid & 63;
  const int wid = tid >> 6;
  const int wm = (wid >> 1) * 64;
  const int wn = (wid & 1) * 64;
  const int row0 = blockIdx.x * 128;
  const int col0 = blockIdx.y * 128;

  f32x4 acc[4][4] = {};

  const u16* ga = A + (size_t)(row0 + (tid >> 3)) * K + (tid & 7) * 8;
  const u16* gb = Bt + (size_t)(col0 + (tid >> 3)) * K + (tid & 7) * 8;
  u16* la = As + tid * 8;
  u16* lb = Bs + tid * 8;

  for (int kt = 0; kt < K / 64; ++kt) {
#pragma unroll
    for (int i = 0; i < 4; ++i) {
      gload_lds16(ga + (size_t)i * 32 * K + kt * 64, la + i * 2048);
      gload_lds16(gb + (size_t)i * 32 * K + kt * 64, lb + i * 2048);
    }
    __syncthreads();
#pragma unroll
    for (int ks = 0; ks < 2; ++ks) {
      short8 af[4], bf[4];
      const int ko = ks * 32 + (lane >> 4) * 8;
#pragma unroll
      for (int mt = 0; mt < 4; ++mt)
        af[mt] = *(const short8*)(As + (wm + mt * 16 + (lane & 15)) * 64 + ko);
#pragma unroll
      for (int nt = 0; nt < 4; ++nt)
        bf[nt] = *(const short8*)(Bs + (wn + nt * 16 + (lane & 15)) * 64 + ko);
#pragma unroll
      for (int mt = 0; mt < 4; ++mt)
#pragma unroll
        for (int nt = 0; nt < 4; ++nt)
          acc[mt][nt] = __builtin_amdgcn_mfma_f32_16x16x32_bf16(af[mt], bf[nt], acc[mt][nt], 0, 0, 0);
    }
    __syncthreads();
  }

#pragma unroll
  for (int nt = 0; nt < 4; ++nt) {
    const int col = col0 + wn + nt * 16 + (lane & 15);
    const float bv = bias[col];
    if (MODE == 0) {
      const int part = col >> 10;
      const int h = (col >> 6) & 15;
      const int d = col & 63;
      u16* dp = part == 0 ? qb : kb;
#pragma unroll
      for (int mt = 0; mt < 4; ++mt) {
#pragma unroll
        for (int r = 0; r < 4; ++r) {
          const int row = row0 + wm + mt * 16 + (lane >> 4) * 4 + r;
          const int bidx = row >> 11;
          const int tt = row & 2047;
          const u16 val = f2bf(acc[mt][nt][r] + bv);
          if (part == 2)
            vb[((size_t)((bidx << 4) + h) * 64 + d) * 2048 + tt] = val;
          else
            dp[((size_t)((bidx << 4) + h) * 2048 + tt) * 64 + d] = val;
        }
      }
    } else {
#pragma unroll
      for (int mt = 0; mt < 4; ++mt) {
#pragma unroll
        for (int r = 0; r < 4; ++r) {
          const int row = row0 + wm + mt * 16 + (lane >> 4) * 4 + r;
          outp[(size_t)row * NSIZE + col] = acc[mt][nt][r] + bv;
        }
      }
    }
  }
}

// -------- flash attention: 32 q-rows/wave, equal-cost sequential pairing ----
// grid (16, 32): block x processes 128-row q-tiles {15-x, x} SEQUENTIALLY ->
// every block exactly 36 kv-iters (2 equal blocks/CU, no tail).
// Each wave owns 32 q-rows = two independent 16-row groups (ILP for the
// softmax chain); K/V LDS fragments shared by both groups (per-row DS halved).
// Swapped QK^T (S^T = mfma(K,Q)) keeps softmax in-lane; row-sums via
// ones-MFMA; defer-max skips rescale when __all(max growth <= 44 raw).
__global__ __launch_bounds__(256, 3) void attn_fwd(const u16* __restrict__ Qb,
                                                   const u16* __restrict__ Kb,
                                                   const u16* __restrict__ Vtb,
                                                   u16* __restrict__ Yb) {
  __shared__ u16 Ks[2][64 * 64];
  __shared__ u16 Vs[2][64 * 64];
  __shared__ u16 Ps[4][2048];
  const int bh = blockIdx.y;
  const int tid = threadIdx.x;
  const int lane = tid & 63;
  const int wid = tid >> 6;
  const int l15 = lane & 15;
  const int g4 = lane >> 4;
  const size_t bhq = (size_t)bh * 2048 * 64;
  const u16* Kbase = Kb + bhq;
  const u16* Vbase = Vtb + bhq;  // [64 d][2048 t] per bh
  const float C2 = 0.18033688011112042f;  // 0.125 * log2(e)
  u16* Pw = &Ps[wid][0];

  short8 ones;
#pragma unroll
  for (int i = 0; i < 8; ++i) ones[i] = (short)0x3F80;  // bf16 1.0

#pragma unroll
  for (int ti = 0; ti < 2; ++ti) {
    const int T = (ti == 0) ? (15 - (int)blockIdx.x) : (int)blockIdx.x;
    const int q0 = T * 128;
    const int wrow0 = q0 + wid * 32;   // wave's 32 q-rows
    const int nkv = 2 * T + 2;

    short8 qf[2][2];
#pragma unroll
    for (int g = 0; g < 2; ++g) {
      const u16* qp = Qb + bhq + (size_t)(wrow0 + g * 16 + l15) * 64 + g4 * 8;
      qf[g][0] = *(const short8*)(qp);
      qf[g][1] = *(const short8*)(qp + 32);
    }
    f32x4 accy[2][4] = {};
    float m_q[2] = {-1e30f, -1e30f};
    float m_r[2][4] = {{-1e30f, -1e30f, -1e30f, -1e30f}, {-1e30f, -1e30f, -1e30f, -1e30f}};
    float l_r[2][4] = {};

    int cur = 0;
#pragma unroll
    for (int cc = 0; cc < 2; ++cc) {
      const int c = tid + cc * 256;
      const int srow = c >> 3;
      const int sblk = (c & 7) ^ (srow & 7);
      gload_lds16(Kbase + srow * 64 + sblk * 8, Ks[0] + c * 8);
      gload_lds16(Vbase + (size_t)srow * 2048 + sblk * 8, Vs[0] + c * 8);
    }

    for (int kv = 0; kv < nkv; ++kv) {
      const int kv0 = kv * 64;
      if (kv + 1 < nkv) {
        const int nx0 = kv0 + 64;
#pragma unroll
        for (int cc = 0; cc < 2; ++cc) {
          const int c = tid + cc * 256;
          const int srow = c >> 3;
          const int sblk = (c & 7) ^ (srow & 7);
          gload_lds16(Kbase + (size_t)(nx0 + srow) * 64 + sblk * 8, Ks[cur ^ 1] + c * 8);
          gload_lds16(Vbase + (size_t)srow * 2048 + nx0 + sblk * 8, Vs[cur ^ 1] + c * 8);
        }
        asm volatile("s_waitcnt vmcnt(4)" ::: "memory");
      } else {
        asm volatile("s_waitcnt vmcnt(0)" ::: "memory");
      }
      __builtin_amdgcn_s_barrier();
      asm volatile("" ::: "memory");

      if (kv0 <= wrow0 + 31) {  // wave-uniform skip of fully-masked tiles
        const u16* Kt = Ks[cur];
        const u16* Vt = Vs[cur];

        // ---- S^T = K Q^T for both groups; kf shared ----
        f32x4 s[2][4];
#pragma unroll
        for (int nt = 0; nt < 4; ++nt) {
          const int R = nt * 16 + l15;
          const int sw = (R & 7) << 4;
          short8 kf0 = *(const short8*)((const char*)Kt + R * 128 + ((g4 * 16) ^ sw));
          short8 kf1 = *(const short8*)((const char*)Kt + R * 128 + ((64 + g4 * 16) ^ sw));
          f32x4 z0 = __builtin_amdgcn_mfma_f32_16x16x32_bf16(kf0, qf[0][0], f32x4{}, 0, 0, 0);
          s[0][nt] = __builtin_amdgcn_mfma_f32_16x16x32_bf16(kf1, qf[0][1], z0, 0, 0, 0);
          f32x4 z1 = __builtin_amdgcn_mfma_f32_16x16x32_bf16(kf0, qf[1][0], f32x4{}, 0, 0, 0);
          s[1][nt] = __builtin_amdgcn_mfma_f32_16x16x32_bf16(kf1, qf[1][1], z1, 0, 0, 0);
        }

        // ---- per-group: mask, in-lane max, defer-max rescale, exp ----
#pragma unroll
        for (int g = 0; g < 2; ++g) {
          const int grow0 = wrow0 + g * 16;
          if (kv0 + 63 > grow0) {  // mask only diagonal-straddling tiles
            const int qg = grow0 + l15;
#pragma unroll
            for (int nt = 0; nt < 4; ++nt) {
              const int kbase = kv0 + nt * 16 + g4 * 4;
#pragma unroll
              for (int r = 0; r < 4; ++r)
                if (kbase + r > qg) s[g][nt][r] = -1e30f;
            }
          }
          float mx = fmaxf(fmaxf(fmaxf(s[g][0][0], s[g][0][1]), fmaxf(s[g][0][2], s[g][0][3])),
                           fmaxf(fmaxf(s[g][1][0], s[g][1][1]), fmaxf(s[g][1][2], s[g][1][3])));
          mx = fmaxf(mx, fmaxf(fmaxf(fmaxf(s[g][2][0], s[g][2][1]), fmaxf(s[g][2][2], s[g][2][3])),
                               fmaxf(fmaxf(s[g][3][0], s[g][3][1]), fmaxf(s[g][3][2], s[g][3][3]))));
          mx = fmaxf(mx, __shfl_xor(mx, 16));
          mx = fmaxf(mx, __shfl_xor(mx, 32));
          if (!__all(mx <= m_q[g] + 44.0f)) {   // rescale path (rare)
            m_q[g] = fmaxf(m_q[g], mx);
#pragma unroll
            for (int rr = 0; rr < 4; ++rr) {
              const float mn = __shfl(m_q[g], g4 * 4 + rr);
              const float al = __builtin_amdgcn_exp2f((m_r[g][rr] - mn) * C2);
              m_r[g][rr] = mn;
              l_r[g][rr] *= al;
#pragma unroll
              for (int nt = 0; nt < 4; ++nt) accy[g][nt][rr] *= al;
            }
          }
          const float m2 = m_q[g] * C2;
#pragma unroll
          for (int nt = 0; nt < 4; ++nt)
#pragma unroll
            for (int r = 0; r < 4; ++r)
              s[g][nt][r] = __builtin_amdgcn_exp2f(fmaf(s[g][nt][r], C2, -m2));

          // ---- P -> per-wave LDS (packed b64, swizzled) ----
#pragma unroll
          for (int nt = 0; nt < 4; ++nt) {
            const unsigned lo = f2bf(s[g][nt][0]) | ((unsigned)f2bf(s[g][nt][1]) << 16);
            const unsigned hi = f2bf(s[g][nt][2]) | ((unsigned)f2bf(s[g][nt][3]) << 16);
            const int rowL = g * 16 + l15;
            const int colB = nt * 32 + g4 * 8;
            *(uint2*)((char*)Pw + rowL * 128 + (colB ^ ((rowL & 7) << 4))) = make_uint2(lo, hi);
          }
        }

        // ---- read P fragments, psum via ones-MFMA, PV (vf shared) ----
        short8 pf[2][2];
#pragma unroll
        for (int g = 0; g < 2; ++g) {
          const int rowL = g * 16 + l15;
          const int sw = (rowL & 7) << 4;
          pf[g][0] = *(const short8*)((const char*)Pw + rowL * 128 + ((g4 * 16) ^ sw));
          pf[g][1] = *(const short8*)((const char*)Pw + rowL * 128 + ((64 + g4 * 16) ^ sw));
        }
#pragma unroll
        for (int g = 0; g < 2; ++g) {
          f32x4 ps = __builtin_amdgcn_mfma_f32_16x16x32_bf16(pf[g][0], ones, f32x4{}, 0, 0, 0);
          ps = __builtin_amdgcn_mfma_f32_16x16x32_bf16(pf[g][1], ones, ps, 0, 0, 0);
#pragma unroll
          for (int rr = 0; rr < 4; ++rr) l_r[g][rr] += ps[rr];
        }
#pragma unroll
        for (int nt = 0; nt < 4; ++nt) {
          const int R = nt * 16 + l15;
          const int sw = (R & 7) << 4;
          short8 vf0 = *(const short8*)((const char*)Vt + R * 128 + ((g4 * 16) ^ sw));
          short8 vf1 = *(const short8*)((const char*)Vt + R * 128 + ((64 + g4 * 16) ^ sw));
#pragma unroll
          for (int g = 0; g < 2; ++g) {
            accy[g][nt] = __builtin_amdgcn_mfma_f32_16x16x32_bf16(pf[g][0], vf0, accy[g][nt], 0, 0, 0);
            accy[g][nt] = __builtin_amdgcn_mfma_f32_16x16x32_bf16(pf[g][1], vf1, accy[g][nt], 0, 0, 0);
          }
        }
      }

      asm volatile("" ::: "memory");
      __builtin_amdgcn_s_barrier();
      cur ^= 1;
    }

    // ---- epilogue: normalize, write y [b][t][h*64+d] bf16 ----
#pragma unroll
    for (int g = 0; g < 2; ++g) {
#pragma unroll
      for (int r = 0; r < 4; ++r) {
        const int row = wrow0 + g * 16 + g4 * 4 + r;
        const float inv = 1.0f / l_r[g][r];
        const size_t base = ((size_t)(bh >> 4) * 2048 + row) * 1024 + (bh & 15) * 64;
#pragma unroll
        for (int nt = 0; nt < 4; ++nt)
          Yb[base + nt * 16 + l15] = f2bf(accy[g][nt][r] * inv);
      }
    }
  }
}

extern "C" void kernel_launch(void* const* d_in, const int* in_sizes, int n_in,
                              void* d_out, int out_size, void* d_ws, size_t ws_size,
                              hipStream_t stream) {
  const float* x      = (const float*)d_in[0];
  const float* w_attn = (const float*)d_in[1];
  const float* b_attn = (const float*)d_in[2];
  const float* w_proj = (const float*)d_in[3];
  const float* b_proj = (const float*)d_in[4];
  float* out = (float*)d_out;
  char* ws = (char*)d_ws;

  u16* xb  = (u16*)(ws + (size_t)0);           // 8 MB: x bf16 [4096][1024]
  u16* wTa = (u16*)(ws + ((size_t)8  << 20));  // 6 MB: w_attn^T bf16 [3072][1024]
  u16* wTp = (u16*)(ws + ((size_t)14 << 20));  // 2 MB: w_proj^T bf16 [1024][1024]
  u16* qb  = (u16*)(ws + ((size_t)16 << 20));  // 8 MB: Q [32][2048][64]
  u16* kb  = (u16*)(ws + ((size_t)24 << 20));  // 8 MB: K [32][2048][64]
  u16* vb  = (u16*)(ws + ((size_t)32 << 20));  // 8 MB: V^T [32][64][2048]
  u16* yb  = (u16*)(ws + ((size_t)40 << 20));  // 8 MB: y bf16 [4096][1024]

  cvt_bf16<<<2048, 256, 0, stream>>>(x, xb, 2 * 2048 * 1024);
  transpose_bf16<1024, 3072><<<dim3(48, 16), 256, 0, stream>>>(w_attn, wTa);
  transpose_bf16<1024, 1024><<<dim3(16, 16), 256, 0, stream>>>(w_proj, wTp);
  gemm_bt<3072, 0><<<dim3(32, 24), 256, 0, stream>>>(xb, wTa, b_attn, qb, kb, vb, nullptr);
  attn_fwd<<<dim3(16, 32), 256, 0, stream>>>(qb, kb, vb, yb);
  gemm_bt<1024, 1><<<dim3(32, 8), 256, 0, stream>>>(yb, wTp, b_proj, nullptr, nullptr, nullptr, out);
}

// Round 7
// 135.407 us; speedup vs baseline: 1.1611x; 1.1611x over previous
//
#include <hip/hip_runtime.h>
#include <hip/hip_bf16.h>
#include <math.h>

typedef __attribute__((ext_vector_type(8))) short short8;
typedef __attribute__((ext_vector_type(4))) float f32x4;
typedef unsigned short u16;

static __device__ __forceinline__ u16 f2bf(float f) {
  union { float f; unsigned u; } v; v.f = f;
  unsigned r = v.u + 0x7fffu + ((v.u >> 16) & 1u);
  return (u16)(r >> 16);
}

static __device__ __forceinline__ void gload_lds16(const void* g, void* l) {
  __builtin_amdgcn_global_load_lds(
      (const __attribute__((address_space(1))) void*)g,
      (__attribute__((address_space(3))) void*)l, 16, 0, 0);
}

// ---------------- fp32 -> bf16 convert (8 elems/thread) ----------------
__global__ __launch_bounds__(256) void cvt_bf16(const float* __restrict__ in,
                                                u16* __restrict__ out, int n) {
  int i = (blockIdx.x * 256 + threadIdx.x) * 8;
  if (i >= n) return;
  float4 a = *(const float4*)(in + i);
  float4 b = *(const float4*)(in + i + 4);
  uint4 pk;
  pk.x = f2bf(a.x) | ((unsigned)f2bf(a.y) << 16);
  pk.y = f2bf(a.z) | ((unsigned)f2bf(a.w) << 16);
  pk.z = f2bf(b.x) | ((unsigned)f2bf(b.y) << 16);
  pk.w = f2bf(b.z) | ((unsigned)f2bf(b.w) << 16);
  *(uint4*)(out + i) = pk;
}

// -------- transpose fp32 W[KD][ND] -> bf16 WT[ND][KD] (tiled 64x64) --------
template<int KD, int ND>
__global__ __launch_bounds__(256) void transpose_bf16(const float* __restrict__ W,
                                                      u16* __restrict__ WT) {
  __shared__ float tile[64][65];
  const int c0 = blockIdx.x * 64;
  const int k0 = blockIdx.y * 64;
  const int t = threadIdx.x;
  const int lr = t >> 2;
  const int lc = (t & 3) * 16;
  const float* src = W + (size_t)(k0 + lr) * ND + c0 + lc;
#pragma unroll
  for (int i = 0; i < 16; i += 4) {
    float4 v = *(const float4*)(src + i);
    tile[lr][lc + i] = v.x; tile[lr][lc + i + 1] = v.y;
    tile[lr][lc + i + 2] = v.z; tile[lr][lc + i + 3] = v.w;
  }
  __syncthreads();
  unsigned pk[8];
#pragma unroll
  for (int j = 0; j < 8; ++j) {
    u16 lo = f2bf(tile[lc + 2 * j][lr]);
    u16 hi = f2bf(tile[lc + 2 * j + 1][lr]);
    pk[j] = lo | ((unsigned)hi << 16);
  }
  u16* dst = WT + (size_t)(c0 + lr) * KD + k0 + lc;
  *(uint4*)(dst) = make_uint4(pk[0], pk[1], pk[2], pk[3]);
  *(uint4*)(dst + 8) = make_uint4(pk[4], pk[5], pk[6], pk[7]);
}

// -------- GEMM: C[M,N] = A[M,1024] * Bt[N,1024]^T + bias --------
// MODE 0: scatter to q/k (bf16 [bh][t][64]) and V TRANSPOSED ([bh][d][t]);
// MODE 1: fp32 out [M][NSIZE]
template<int NSIZE, int MODE>
__global__ __launch_bounds__(256) void gemm_bt(const u16* __restrict__ A,
                                               const u16* __restrict__ Bt,
                                               const float* __restrict__ bias,
                                               u16* __restrict__ qb,
                                               u16* __restrict__ kb,
                                               u16* __restrict__ vb,
                                               float* __restrict__ outp) {
  constexpr int K = 1024;
  __shared__ u16 As[128 * 64];
  __shared__ u16 Bs[128 * 64];
  const int tid = threadIdx.x;
  const int lane = tid & 63;
  const int wid = tid >> 6;
  const int wm = (wid >> 1) * 64;
  const int wn = (wid & 1) * 64;
  const int row0 = blockIdx.x * 128;
  const int col0 = blockIdx.y * 128;

  f32x4 acc[4][4] = {};

  const u16* ga = A + (size_t)(row0 + (tid >> 3)) * K + (tid & 7) * 8;
  const u16* gb = Bt + (size_t)(col0 + (tid >> 3)) * K + (tid & 7) * 8;
  u16* la = As + tid * 8;
  u16* lb = Bs + tid * 8;

  for (int kt = 0; kt < K / 64; ++kt) {
#pragma unroll
    for (int i = 0; i < 4; ++i) {
      gload_lds16(ga + (size_t)i * 32 * K + kt * 64, la + i * 2048);
      gload_lds16(gb + (size_t)i * 32 * K + kt * 64, lb + i * 2048);
    }
    __syncthreads();
#pragma unroll
    for (int ks = 0; ks < 2; ++ks) {
      short8 af[4], bf[4];
      const int ko = ks * 32 + (lane >> 4) * 8;
#pragma unroll
      for (int mt = 0; mt < 4; ++mt)
        af[mt] = *(const short8*)(As + (wm + mt * 16 + (lane & 15)) * 64 + ko);
#pragma unroll
      for (int nt = 0; nt < 4; ++nt)
        bf[nt] = *(const short8*)(Bs + (wn + nt * 16 + (lane & 15)) * 64 + ko);
#pragma unroll
      for (int mt = 0; mt < 4; ++mt)
#pragma unroll
        for (int nt = 0; nt < 4; ++nt)
          acc[mt][nt] = __builtin_amdgcn_mfma_f32_16x16x32_bf16(af[mt], bf[nt], acc[mt][nt], 0, 0, 0);
    }
    __syncthreads();
  }

#pragma unroll
  for (int nt = 0; nt < 4; ++nt) {
    const int col = col0 + wn + nt * 16 + (lane & 15);
    const float bv = bias[col];
    if (MODE == 0) {
      const int part = col >> 10;
      const int h = (col >> 6) & 15;
      const int d = col & 63;
      u16* dp = part == 0 ? qb : kb;
#pragma unroll
      for (int mt = 0; mt < 4; ++mt) {
#pragma unroll
        for (int r = 0; r < 4; ++r) {
          const int row = row0 + wm + mt * 16 + (lane >> 4) * 4 + r;
          const int bidx = row >> 11;
          const int tt = row & 2047;
          const u16 val = f2bf(acc[mt][nt][r] + bv);
          if (part == 2)
            vb[((size_t)((bidx << 4) + h) * 64 + d) * 2048 + tt] = val;
          else
            dp[((size_t)((bidx << 4) + h) * 2048 + tt) * 64 + d] = val;
        }
      }
    } else {
#pragma unroll
      for (int mt = 0; mt < 4; ++mt) {
#pragma unroll
        for (int r = 0; r < 4; ++r) {
          const int row = row0 + wm + mt * 16 + (lane >> 4) * 4 + r;
          outp[(size_t)row * NSIZE + col] = acc[mt][nt][r] + bv;
        }
      }
    }
  }
}

// ---------------- work-queue counter zeroing ----------------
__global__ void zero_u32(unsigned* p) { *p = 0u; }

// -------- flash attention: persistent blocks + dynamic work queue --------
// 768 blocks (3/CU, 12 waves/CU sustained). Items = (bh, T) sorted
// longest-first: item i -> T = 31 - (i>>5), bh = i&31 (1024 items).
// Compute body identical to R5 (measured 56.8us): 4 waves x 16 q-rows,
// swapped QK^T (S^T = mfma(K,Q)) in-lane softmax, ones-MFMA row sums,
// K [t][64] / V^T [d][t] XOR-swizzled, double-buffered counted-vmcnt staging.
__global__ __launch_bounds__(256, 3) void attn_fwd(const u16* __restrict__ Qb,
                                                   const u16* __restrict__ Kb,
                                                   const u16* __restrict__ Vtb,
                                                   u16* __restrict__ Yb,
                                                   unsigned* __restrict__ cnt) {
  __shared__ u16 Ks[2][64 * 64];
  __shared__ u16 Vs[2][64 * 64];
  __shared__ u16 Ps[4][1024];
  __shared__ int sh_item;
  const int tid = threadIdx.x;
  const int lane = tid & 63;
  const int wid = tid >> 6;
  const int l15 = lane & 15;
  const int g4 = lane >> 4;
  const float C2 = 0.18033688011112042f;  // 0.125 * log2(e)
  u16* Pw = &Ps[wid][0];

  short8 ones;
#pragma unroll
  for (int i = 0; i < 8; ++i) ones[i] = (short)0x3F80;  // bf16 1.0

  for (;;) {
    if (tid == 0) sh_item = (int)atomicAdd(cnt, 1u);
    __syncthreads();
    const int item = sh_item;
    if (item >= 1024) return;
    const int T = 31 - (item >> 5);     // longest-first
    const int bh = item & 31;
    const int q0 = T * 64;
    const size_t bhq = (size_t)bh * 2048 * 64;
    const u16* Kbase = Kb + bhq;
    const u16* Vbase = Vtb + bhq;       // [64 d][2048 t] per bh
    const int wrow0 = q0 + wid * 16;
    const int nkv = T + 1;

    short8 qf[2];
    {
      const u16* qp = Qb + bhq + (size_t)(wrow0 + l15) * 64 + g4 * 8;
      qf[0] = *(const short8*)(qp);
      qf[1] = *(const short8*)(qp + 32);
    }
    f32x4 accy[4] = {};
    float m_q = -1e30f;
    float m_r[4] = {-1e30f, -1e30f, -1e30f, -1e30f};
    float l_r[4] = {0.f, 0.f, 0.f, 0.f};

    int cur = 0;
#pragma unroll
    for (int cc = 0; cc < 2; ++cc) {
      const int c = tid + cc * 256;
      const int srow = c >> 3;
      const int sblk = (c & 7) ^ (srow & 7);
      gload_lds16(Kbase + srow * 64 + sblk * 8, Ks[0] + c * 8);
      gload_lds16(Vbase + (size_t)srow * 2048 + sblk * 8, Vs[0] + c * 8);
    }

    for (int kv = 0; kv < nkv; ++kv) {
      const int kv0 = kv * 64;
      if (kv + 1 < nkv) {
        const int nx0 = kv0 + 64;
#pragma unroll
        for (int cc = 0; cc < 2; ++cc) {
          const int c = tid + cc * 256;
          const int srow = c >> 3;
          const int sblk = (c & 7) ^ (srow & 7);
          gload_lds16(Kbase + (size_t)(nx0 + srow) * 64 + sblk * 8, Ks[cur ^ 1] + c * 8);
          gload_lds16(Vbase + (size_t)srow * 2048 + nx0 + sblk * 8, Vs[cur ^ 1] + c * 8);
        }
        asm volatile("s_waitcnt vmcnt(4)" ::: "memory");
      } else {
        asm volatile("s_waitcnt vmcnt(0)" ::: "memory");
      }
      __builtin_amdgcn_s_barrier();
      asm volatile("" ::: "memory");

      const u16* Kt = Ks[cur];
      const u16* Vt = Vs[cur];
      // ---- S^T = K Q^T : s[nt][r] = S[q=l15][k = kv0 + nt*16 + g4*4 + r] ----
      f32x4 s[4];
#pragma unroll
      for (int nt = 0; nt < 4; ++nt) {
        f32x4 z = {};
#pragma unroll
        for (int ks = 0; ks < 2; ++ks) {
          const int R = nt * 16 + l15;
          const int B = ks * 64 + g4 * 16;
          short8 kf = *(const short8*)((const char*)Kt + R * 128 + (B ^ ((R & 7) << 4)));
          z = __builtin_amdgcn_mfma_f32_16x16x32_bf16(kf, qf[ks], z, 0, 0, 0);
        }
        s[nt] = z;
      }

      // ---- causal mask (diagonal-straddling tiles only) ----
      if (kv0 + 63 > wrow0) {
        const int qg = wrow0 + l15;
#pragma unroll
        for (int nt = 0; nt < 4; ++nt) {
          const int kbase = kv0 + nt * 16 + g4 * 4;
#pragma unroll
          for (int r = 0; r < 4; ++r)
            if (kbase + r > qg) s[nt][r] = -1e30f;
        }
      }

      // ---- in-lane row max (tree) + 2-shuffle butterfly over g4 ----
      f32x4 mt4;
#pragma unroll
      for (int r = 0; r < 4; ++r)
        mt4[r] = fmaxf(fmaxf(s[0][r], s[1][r]), fmaxf(s[2][r], s[3][r]));
      float mx = fmaxf(fmaxf(mt4[0], mt4[1]), fmaxf(mt4[2], mt4[3]));
      mx = fmaxf(mx, __shfl_xor(mx, 16));
      mx = fmaxf(mx, __shfl_xor(mx, 32));
      const float mnew = fmaxf(m_q, mx);
      const float m2 = mnew * C2;
#pragma unroll
      for (int nt = 0; nt < 4; ++nt)
#pragma unroll
        for (int r = 0; r < 4; ++r)
          s[nt][r] = __builtin_amdgcn_exp2f(fmaf(s[nt][r], C2, -m2));
      m_q = mnew;

      // ---- redistribute new max to accy layout (q = g4*4 + rr), rescale ----
      float alpha_r[4];
#pragma unroll
      for (int rr = 0; rr < 4; ++rr) {
        const float mn = __shfl(mnew, g4 * 4 + rr);
        alpha_r[rr] = __builtin_amdgcn_exp2f((m_r[rr] - mn) * C2);
        m_r[rr] = mn;
      }
#pragma unroll
      for (int nt = 0; nt < 4; ++nt)
#pragma unroll
        for (int rr = 0; rr < 4; ++rr) accy[nt][rr] *= alpha_r[rr];

      // ---- P -> per-wave LDS (packed b64, swizzled) ----
#pragma unroll
      for (int nt = 0; nt < 4; ++nt) {
        const unsigned lo = f2bf(s[nt][0]) | ((unsigned)f2bf(s[nt][1]) << 16);
        const unsigned hi = f2bf(s[nt][2]) | ((unsigned)f2bf(s[nt][3]) << 16);
        const int colB = nt * 32 + g4 * 8;
        *(uint2*)((char*)Pw + l15 * 128 + (colB ^ ((l15 & 7) << 4))) = make_uint2(lo, hi);
      }

      // ---- read P fragments, row-sums via ones-MFMA, PV ----
      short8 pf[2];
#pragma unroll
      for (int ks = 0; ks < 2; ++ks) {
        const int B = ks * 64 + g4 * 16;
        pf[ks] = *(const short8*)((const char*)Pw + l15 * 128 + (B ^ ((l15 & 7) << 4)));
      }
      f32x4 psum = {};
      psum = __builtin_amdgcn_mfma_f32_16x16x32_bf16(pf[0], ones, psum, 0, 0, 0);
      psum = __builtin_amdgcn_mfma_f32_16x16x32_bf16(pf[1], ones, psum, 0, 0, 0);
#pragma unroll
      for (int rr = 0; rr < 4; ++rr) l_r[rr] = l_r[rr] * alpha_r[rr] + psum[rr];

#pragma unroll
      for (int ks = 0; ks < 2; ++ks) {
#pragma unroll
        for (int nt = 0; nt < 4; ++nt) {
          const int R = nt * 16 + l15;
          const int B = ks * 64 + g4 * 16;
          short8 vf = *(const short8*)((const char*)Vt + R * 128 + (B ^ ((R & 7) << 4)));
          accy[nt] = __builtin_amdgcn_mfma_f32_16x16x32_bf16(pf[ks], vf, accy[nt], 0, 0, 0);
        }
      }

      asm volatile("" ::: "memory");
      __builtin_amdgcn_s_barrier();
      cur ^= 1;
    }

    // ---- epilogue: normalize (l already in accy layout), write y bf16 ----
#pragma unroll
    for (int r = 0; r < 4; ++r) {
      const int row = wrow0 + g4 * 4 + r;
      const float inv = 1.0f / l_r[r];
      const size_t base = ((size_t)(bh >> 4) * 2048 + row) * 1024 + (bh & 15) * 64;
#pragma unroll
      for (int nt = 0; nt < 4; ++nt)
        Yb[base + nt * 16 + l15] = f2bf(accy[nt][r] * inv);
    }
    __syncthreads();  // protect sh_item before next grab
  }
}

extern "C" void kernel_launch(void* const* d_in, const int* in_sizes, int n_in,
                              void* d_out, int out_size, void* d_ws, size_t ws_size,
                              hipStream_t stream) {
  const float* x      = (const float*)d_in[0];
  const float* w_attn = (const float*)d_in[1];
  const float* b_attn = (const float*)d_in[2];
  const float* w_proj = (const float*)d_in[3];
  const float* b_proj = (const float*)d_in[4];
  float* out = (float*)d_out;
  char* ws = (char*)d_ws;

  u16* xb  = (u16*)(ws + (size_t)0);           // 8 MB: x bf16 [4096][1024]
  u16* wTa = (u16*)(ws + ((size_t)8  << 20));  // 6 MB: w_attn^T bf16 [3072][1024]
  u16* wTp = (u16*)(ws + ((size_t)14 << 20));  // 2 MB: w_proj^T bf16 [1024][1024]
  u16* qb  = (u16*)(ws + ((size_t)16 << 20));  // 8 MB: Q [32][2048][64]
  u16* kb  = (u16*)(ws + ((size_t)24 << 20));  // 8 MB: K [32][2048][64]
  u16* vb  = (u16*)(ws + ((size_t)32 << 20));  // 8 MB: V^T [32][64][2048]
  u16* yb  = (u16*)(ws + ((size_t)40 << 20));  // 8 MB: y bf16 [4096][1024]
  // work-queue counter reuses the wTa region (dead after the QKV GEMM)
  unsigned* cnt = (unsigned*)(ws + ((size_t)8 << 20));

  cvt_bf16<<<2048, 256, 0, stream>>>(x, xb, 2 * 2048 * 1024);
  transpose_bf16<1024, 3072><<<dim3(48, 16), 256, 0, stream>>>(w_attn, wTa);
  transpose_bf16<1024, 1024><<<dim3(16, 16), 256, 0, stream>>>(w_proj, wTp);
  gemm_bt<3072, 0><<<dim3(32, 24), 256, 0, stream>>>(xb, wTa, b_attn, qb, kb, vb, nullptr);
  zero_u32<<<1, 1, 0, stream>>>(cnt);
  attn_fwd<<<768, 256, 0, stream>>>(qb, kb, vb, yb, cnt);
  gemm_bt<1024, 1><<<dim3(32, 8), 256, 0, stream>>>(yb, wTp, b_proj, nullptr, nullptr, nullptr, out);
}

// Round 8
// 129.590 us; speedup vs baseline: 1.2132x; 1.0449x over previous
//
#include <hip/hip_runtime.h>
#include <hip/hip_bf16.h>
#include <math.h>

typedef __attribute__((ext_vector_type(8))) short short8;
typedef __attribute__((ext_vector_type(4))) float f32x4;
typedef unsigned short u16;

static __device__ __forceinline__ u16 f2bf(float f) {
  union { float f; unsigned u; } v; v.f = f;
  unsigned r = v.u + 0x7fffu + ((v.u >> 16) & 1u);
  return (u16)(r >> 16);
}

static __device__ __forceinline__ float bf2f(u16 h) {
  union { unsigned u; float f; } v; v.u = ((unsigned)h) << 16;
  return v.f;
}

static __device__ __forceinline__ void gload_lds16(const void* g, void* l) {
  __builtin_amdgcn_global_load_lds(
      (const __attribute__((address_space(1))) void*)g,
      (__attribute__((address_space(3))) void*)l, 16, 0, 0);
}

// ---------------- fp32 -> bf16 convert (8 elems/thread) ----------------
__global__ __launch_bounds__(256) void cvt_bf16(const float* __restrict__ in,
                                                u16* __restrict__ out, int n) {
  int i = (blockIdx.x * 256 + threadIdx.x) * 8;
  if (i >= n) return;
  float4 a = *(const float4*)(in + i);
  float4 b = *(const float4*)(in + i + 4);
  uint4 pk;
  pk.x = f2bf(a.x) | ((unsigned)f2bf(a.y) << 16);
  pk.y = f2bf(a.z) | ((unsigned)f2bf(a.w) << 16);
  pk.z = f2bf(b.x) | ((unsigned)f2bf(b.y) << 16);
  pk.w = f2bf(b.z) | ((unsigned)f2bf(b.w) << 16);
  *(uint4*)(out + i) = pk;
}

// -------- transpose fp32 W[KD][ND] -> bf16 WT[ND][KD] (tiled 64x64) --------
template<int KD, int ND>
__global__ __launch_bounds__(256) void transpose_bf16(const float* __restrict__ W,
                                                      u16* __restrict__ WT) {
  __shared__ float tile[64][65];
  const int c0 = blockIdx.x * 64;
  const int k0 = blockIdx.y * 64;
  const int t = threadIdx.x;
  const int lr = t >> 2;
  const int lc = (t & 3) * 16;
  const float* src = W + (size_t)(k0 + lr) * ND + c0 + lc;
#pragma unroll
  for (int i = 0; i < 16; i += 4) {
    float4 v = *(const float4*)(src + i);
    tile[lr][lc + i] = v.x; tile[lr][lc + i + 1] = v.y;
    tile[lr][lc + i + 2] = v.z; tile[lr][lc + i + 3] = v.w;
  }
  __syncthreads();
  unsigned pk[8];
#pragma unroll
  for (int j = 0; j < 8; ++j) {
    u16 lo = f2bf(tile[lc + 2 * j][lr]);
    u16 hi = f2bf(tile[lc + 2 * j + 1][lr]);
    pk[j] = lo | ((unsigned)hi << 16);
  }
  u16* dst = WT + (size_t)(c0 + lr) * KD + k0 + lc;
  *(uint4*)(dst) = make_uint4(pk[0], pk[1], pk[2], pk[3]);
  *(uint4*)(dst + 8) = make_uint4(pk[4], pk[5], pk[6], pk[7]);
}

// -------- GEMM: C[M,N] = A[M,1024] * Bt[N,1024]^T + bias --------
// MODE 0: scatter to q/k (bf16 [bh][t][64]) and V TRANSPOSED ([bh][d][t]);
// MODE 1: fp32 out [M][NSIZE]
template<int NSIZE, int MODE>
__global__ __launch_bounds__(256) void gemm_bt(const u16* __restrict__ A,
                                               const u16* __restrict__ Bt,
                                               const float* __restrict__ bias,
                                               u16* __restrict__ qb,
                                               u16* __restrict__ kb,
                                               u16* __restrict__ vb,
                                               float* __restrict__ outp) {
  constexpr int K = 1024;
  __shared__ u16 As[128 * 64];
  __shared__ u16 Bs[128 * 64];
  const int tid = threadIdx.x;
  const int lane = tid & 63;
  const int wid = tid >> 6;
  const int wm = (wid >> 1) * 64;
  const int wn = (wid & 1) * 64;
  const int row0 = blockIdx.x * 128;
  const int col0 = blockIdx.y * 128;

  f32x4 acc[4][4] = {};

  const u16* ga = A + (size_t)(row0 + (tid >> 3)) * K + (tid & 7) * 8;
  const u16* gb = Bt + (size_t)(col0 + (tid >> 3)) * K + (tid & 7) * 8;
  u16* la = As + tid * 8;
  u16* lb = Bs + tid * 8;

  for (int kt = 0; kt < K / 64; ++kt) {
#pragma unroll
    for (int i = 0; i < 4; ++i) {
      gload_lds16(ga + (size_t)i * 32 * K + kt * 64, la + i * 2048);
      gload_lds16(gb + (size_t)i * 32 * K + kt * 64, lb + i * 2048);
    }
    __syncthreads();
#pragma unroll
    for (int ks = 0; ks < 2; ++ks) {
      short8 af[4], bf[4];
      const int ko = ks * 32 + (lane >> 4) * 8;
#pragma unroll
      for (int mt = 0; mt < 4; ++mt)
        af[mt] = *(const short8*)(As + (wm + mt * 16 + (lane & 15)) * 64 + ko);
#pragma unroll
      for (int nt = 0; nt < 4; ++nt)
        bf[nt] = *(const short8*)(Bs + (wn + nt * 16 + (lane & 15)) * 64 + ko);
#pragma unroll
      for (int mt = 0; mt < 4; ++mt)
#pragma unroll
        for (int nt = 0; nt < 4; ++nt)
          acc[mt][nt] = __builtin_amdgcn_mfma_f32_16x16x32_bf16(af[mt], bf[nt], acc[mt][nt], 0, 0, 0);
    }
    __syncthreads();
  }

#pragma unroll
  for (int nt = 0; nt < 4; ++nt) {
    const int col = col0 + wn + nt * 16 + (lane & 15);
    const float bv = bias[col];
    if (MODE == 0) {
      const int part = col >> 10;
      const int h = (col >> 6) & 15;
      const int d = col & 63;
      u16* dp = part == 0 ? qb : kb;
#pragma unroll
      for (int mt = 0; mt < 4; ++mt) {
#pragma unroll
        for (int r = 0; r < 4; ++r) {
          const int row = row0 + wm + mt * 16 + (lane >> 4) * 4 + r;
          const int bidx = row >> 11;
          const int tt = row & 2047;
          const u16 val = f2bf(acc[mt][nt][r] + bv);
          if (part == 2)
            vb[((size_t)((bidx << 4) + h) * 64 + d) * 2048 + tt] = val;
          else
            dp[((size_t)((bidx << 4) + h) * 2048 + tt) * 64 + d] = val;
        }
      }
    } else {
#pragma unroll
      for (int mt = 0; mt < 4; ++mt) {
#pragma unroll
        for (int r = 0; r < 4; ++r) {
          const int row = row0 + wm + mt * 16 + (lane >> 4) * 4 + r;
          outp[(size_t)row * NSIZE + col] = acc[mt][nt][r] + bv;
        }
      }
    }
  }
}

// -------- flash attention with split-kv --------
// grid (32 bh, 48 u). Unit map (lengths descending in dispatch order):
//   u in [0,16):  T = 16+u, kv tiles [0,15]   (chunk0 of split, 16 iters)
//   u in [16,32): T = 31-u, kv tiles [0,T]    (unsplit, T<16, T+1 iters)
//   u in [32,48): T = 63-u, kv tiles [16,T]   (chunk1 of split, T-15 iters)
// Split units write normalized-O (bf16) + m + l partials to scratch
// (slot = (bh*16 + T-16)*2 + chunk, stride 8704B); combine kernel merges.
// Compute body verbatim R5 (56.8us measured): 4 waves x 16 q-rows, swapped
// QK^T in-lane softmax, ones-MFMA row sums, XOR-swizzled K/V^T staging,
// double-buffered counted-vmcnt. LDS 40KB -> 4 blocks/CU.
__global__ __launch_bounds__(256, 4) void attn_fwd(const u16* __restrict__ Qb,
                                                   const u16* __restrict__ Kb,
                                                   const u16* __restrict__ Vtb,
                                                   u16* __restrict__ Yb,
                                                   char* __restrict__ pb) {
  __shared__ u16 Ks[2][64 * 64];
  __shared__ u16 Vs[2][64 * 64];
  __shared__ u16 Ps[4][1024];
  const int bh = blockIdx.x;
  const int u = blockIdx.y;
  int T, c0, c1, chunkIdx, split;
  if (u < 16)      { T = 16 + u; c0 = 0;  c1 = 15; chunkIdx = 0; split = 1; }
  else if (u < 32) { T = 31 - u; c0 = 0;  c1 = T;  chunkIdx = 0; split = 0; }
  else             { T = 63 - u; c0 = 16; c1 = T;  chunkIdx = 1; split = 1; }
  const int q0 = T * 64;
  const int tid = threadIdx.x;
  const int lane = tid & 63;
  const int wid = tid >> 6;
  const int l15 = lane & 15;
  const int g4 = lane >> 4;
  const size_t bhq = (size_t)bh * 2048 * 64;
  const u16* Kbase = Kb + bhq;
  const u16* Vbase = Vtb + bhq;  // [64 d][2048 t] per bh
  const float C2 = 0.18033688011112042f;  // 0.125 * log2(e)
  u16* Pw = &Ps[wid][0];
  const int wrow0 = q0 + wid * 16;

  short8 ones;
#pragma unroll
  for (int i = 0; i < 8; ++i) ones[i] = (short)0x3F80;  // bf16 1.0

  short8 qf[2];
  {
    const u16* qp = Qb + bhq + (size_t)(wrow0 + l15) * 64 + g4 * 8;
    qf[0] = *(const short8*)(qp);
    qf[1] = *(const short8*)(qp + 32);
  }
  f32x4 accy[4] = {};
  float m_q = -1e30f;
  float m_r[4] = {-1e30f, -1e30f, -1e30f, -1e30f};
  float l_r[4] = {0.f, 0.f, 0.f, 0.f};

  int cur = 0;
#pragma unroll
  for (int cc = 0; cc < 2; ++cc) {
    const int c = tid + cc * 256;
    const int srow = c >> 3;
    const int sblk = (c & 7) ^ (srow & 7);
    gload_lds16(Kbase + (size_t)(c0 * 64 + srow) * 64 + sblk * 8, Ks[0] + c * 8);
    gload_lds16(Vbase + (size_t)srow * 2048 + c0 * 64 + sblk * 8, Vs[0] + c * 8);
  }

  for (int kv = c0; kv <= c1; ++kv) {
    const int kv0 = kv * 64;
    if (kv < c1) {
      const int nx0 = kv0 + 64;
#pragma unroll
      for (int cc = 0; cc < 2; ++cc) {
        const int c = tid + cc * 256;
        const int srow = c >> 3;
        const int sblk = (c & 7) ^ (srow & 7);
        gload_lds16(Kbase + (size_t)(nx0 + srow) * 64 + sblk * 8, Ks[cur ^ 1] + c * 8);
        gload_lds16(Vbase + (size_t)srow * 2048 + nx0 + sblk * 8, Vs[cur ^ 1] + c * 8);
      }
      asm volatile("s_waitcnt vmcnt(4)" ::: "memory");
    } else {
      asm volatile("s_waitcnt vmcnt(0)" ::: "memory");
    }
    __builtin_amdgcn_s_barrier();
    asm volatile("" ::: "memory");

    const u16* Kt = Ks[cur];
    const u16* Vt = Vs[cur];
    // ---- S^T = K Q^T : s[nt][r] = S[q=l15][k = kv0 + nt*16 + g4*4 + r] ----
    f32x4 s[4];
#pragma unroll
    for (int nt = 0; nt < 4; ++nt) {
      f32x4 z = {};
#pragma unroll
      for (int ks = 0; ks < 2; ++ks) {
        const int R = nt * 16 + l15;
        const int B = ks * 64 + g4 * 16;
        short8 kf = *(const short8*)((const char*)Kt + R * 128 + (B ^ ((R & 7) << 4)));
        z = __builtin_amdgcn_mfma_f32_16x16x32_bf16(kf, qf[ks], z, 0, 0, 0);
      }
      s[nt] = z;
    }

    // ---- causal mask (diagonal-straddling tiles only) ----
    if (kv0 + 63 > wrow0) {
      const int qg = wrow0 + l15;
#pragma unroll
      for (int nt = 0; nt < 4; ++nt) {
        const int kbase = kv0 + nt * 16 + g4 * 4;
#pragma unroll
        for (int r = 0; r < 4; ++r)
          if (kbase + r > qg) s[nt][r] = -1e30f;
      }
    }

    // ---- in-lane row max (tree) + 2-shuffle butterfly over g4 ----
    f32x4 mt4;
#pragma unroll
    for (int r = 0; r < 4; ++r)
      mt4[r] = fmaxf(fmaxf(s[0][r], s[1][r]), fmaxf(s[2][r], s[3][r]));
    float mx = fmaxf(fmaxf(mt4[0], mt4[1]), fmaxf(mt4[2], mt4[3]));
    mx = fmaxf(mx, __shfl_xor(mx, 16));
    mx = fmaxf(mx, __shfl_xor(mx, 32));
    const float mnew = fmaxf(m_q, mx);
    const float m2 = mnew * C2;
#pragma unroll
    for (int nt = 0; nt < 4; ++nt)
#pragma unroll
      for (int r = 0; r < 4; ++r)
        s[nt][r] = __builtin_amdgcn_exp2f(fmaf(s[nt][r], C2, -m2));
    m_q = mnew;

    // ---- redistribute new max to accy layout (q = g4*4 + rr), rescale ----
    float alpha_r[4];
#pragma unroll
    for (int rr = 0; rr < 4; ++rr) {
      const float mn = __shfl(mnew, g4 * 4 + rr);
      alpha_r[rr] = __builtin_amdgcn_exp2f((m_r[rr] - mn) * C2);
      m_r[rr] = mn;
    }
#pragma unroll
    for (int nt = 0; nt < 4; ++nt)
#pragma unroll
      for (int rr = 0; rr < 4; ++rr) accy[nt][rr] *= alpha_r[rr];

    // ---- P -> per-wave LDS (packed b64, swizzled) ----
#pragma unroll
    for (int nt = 0; nt < 4; ++nt) {
      const unsigned lo = f2bf(s[nt][0]) | ((unsigned)f2bf(s[nt][1]) << 16);
      const unsigned hi = f2bf(s[nt][2]) | ((unsigned)f2bf(s[nt][3]) << 16);
      const int colB = nt * 32 + g4 * 8;
      *(uint2*)((char*)Pw + l15 * 128 + (colB ^ ((l15 & 7) << 4))) = make_uint2(lo, hi);
    }

    // ---- read P fragments, row-sums via ones-MFMA, PV ----
    short8 pf[2];
#pragma unroll
    for (int ks = 0; ks < 2; ++ks) {
      const int B = ks * 64 + g4 * 16;
      pf[ks] = *(const short8*)((const char*)Pw + l15 * 128 + (B ^ ((l15 & 7) << 4)));
    }
    f32x4 psum = {};
    psum = __builtin_amdgcn_mfma_f32_16x16x32_bf16(pf[0], ones, psum, 0, 0, 0);
    psum = __builtin_amdgcn_mfma_f32_16x16x32_bf16(pf[1], ones, psum, 0, 0, 0);
#pragma unroll
    for (int rr = 0; rr < 4; ++rr) l_r[rr] = l_r[rr] * alpha_r[rr] + psum[rr];

#pragma unroll
    for (int ks = 0; ks < 2; ++ks) {
#pragma unroll
      for (int nt = 0; nt < 4; ++nt) {
        const int R = nt * 16 + l15;
        const int B = ks * 64 + g4 * 16;
        short8 vf = *(const short8*)((const char*)Vt + R * 128 + (B ^ ((R & 7) << 4)));
        accy[nt] = __builtin_amdgcn_mfma_f32_16x16x32_bf16(pf[ks], vf, accy[nt], 0, 0, 0);
      }
    }

    asm volatile("" ::: "memory");
    __builtin_amdgcn_s_barrier();
    cur ^= 1;
  }

  if (!split) {
    // ---- epilogue: normalize, write y [b][t][h*64+d] bf16 ----
#pragma unroll
    for (int r = 0; r < 4; ++r) {
      const int row = wrow0 + g4 * 4 + r;
      const float inv = 1.0f / l_r[r];
      const size_t base = ((size_t)(bh >> 4) * 2048 + row) * 1024 + (bh & 15) * 64;
#pragma unroll
      for (int nt = 0; nt < 4; ++nt)
        Yb[base + nt * 16 + l15] = f2bf(accy[nt][r] * inv);
    }
  } else {
    // ---- partial epilogue: normalized O (bf16) + m + l to scratch ----
    char* slot = pb + ((size_t)(bh * 16 + (T - 16)) * 2 + chunkIdx) * 8704;
    u16* O = (u16*)slot;
    float* mf = (float*)(slot + 8192);
    float* lf = (float*)(slot + 8448);
#pragma unroll
    for (int r = 0; r < 4; ++r) {
      const int row = wid * 16 + g4 * 4 + r;   // local row 0..63
      const float inv = 1.0f / l_r[r];
#pragma unroll
      for (int nt = 0; nt < 4; ++nt)
        O[row * 64 + nt * 16 + l15] = f2bf(accy[nt][r] * inv);
      if (l15 == 0) { mf[row] = m_r[r]; lf[row] = l_r[r]; }
    }
  }
}

// -------- combine split-kv partials: y = (O0n*l0*w0 + O1n*l1*w1)/(l0w0+l1w1) --
__global__ __launch_bounds__(256) void attn_combine(const char* __restrict__ pb,
                                                    u16* __restrict__ Yb) {
  const int x = blockIdx.x;      // 0..15 -> T = 16+x
  const int bh = blockIdx.y;
  const int T = 16 + x;
  const char* s0 = pb + ((size_t)(bh * 16 + x) * 2) * 8704;
  const char* s1 = s0 + 8704;
  const int tid = threadIdx.x;
  const int row = tid >> 2;        // 0..63
  const int dc = (tid & 3) * 16;   // 0,16,32,48
  const float C2 = 0.18033688011112042f;
  const float m0 = ((const float*)(s0 + 8192))[row];
  const float m1 = ((const float*)(s1 + 8192))[row];
  const float l0 = ((const float*)(s0 + 8448))[row];
  const float l1 = ((const float*)(s1 + 8448))[row];
  const float m = fmaxf(m0, m1);
  const float w0 = __builtin_amdgcn_exp2f((m0 - m) * C2) * l0;
  const float w1 = __builtin_amdgcn_exp2f((m1 - m) * C2) * l1;
  const float inv = 1.0f / (w0 + w1);
  const float a0 = w0 * inv, a1 = w1 * inv;
  const u16* O0 = (const u16*)s0 + row * 64 + dc;
  const u16* O1 = (const u16*)s1 + row * 64 + dc;
  const int qrow = T * 64 + row;
  u16* yp = Yb + ((size_t)(bh >> 4) * 2048 + qrow) * 1024 + (bh & 15) * 64 + dc;
  union { uint4 v; u16 h[8]; } a[2], b[2], o[2];
  a[0].v = *(const uint4*)O0; a[1].v = *(const uint4*)(O0 + 8);
  b[0].v = *(const uint4*)O1; b[1].v = *(const uint4*)(O1 + 8);
#pragma unroll
  for (int j = 0; j < 2; ++j)
#pragma unroll
    for (int i = 0; i < 8; ++i)
      o[j].h[i] = f2bf(bf2f(a[j].h[i]) * a0 + bf2f(b[j].h[i]) * a1);
  *(uint4*)yp = o[0].v;
  *(uint4*)(yp + 8) = o[1].v;
}

extern "C" void kernel_launch(void* const* d_in, const int* in_sizes, int n_in,
                              void* d_out, int out_size, void* d_ws, size_t ws_size,
                              hipStream_t stream) {
  const float* x      = (const float*)d_in[0];
  const float* w_attn = (const float*)d_in[1];
  const float* b_attn = (const float*)d_in[2];
  const float* w_proj = (const float*)d_in[3];
  const float* b_proj = (const float*)d_in[4];
  float* out = (float*)d_out;
  char* ws = (char*)d_ws;

  u16* xb  = (u16*)(ws + (size_t)0);           // 8 MB: x bf16 [4096][1024]
  u16* wTa = (u16*)(ws + ((size_t)8  << 20));  // 6 MB: w_attn^T bf16 [3072][1024]
  u16* wTp = (u16*)(ws + ((size_t)14 << 20));  // 2 MB: w_proj^T bf16 [1024][1024]
  u16* qb  = (u16*)(ws + ((size_t)16 << 20));  // 8 MB: Q [32][2048][64]
  u16* kb  = (u16*)(ws + ((size_t)24 << 20));  // 8 MB: K [32][2048][64]
  u16* vb  = (u16*)(ws + ((size_t)32 << 20));  // 8 MB: V^T [32][64][2048]
  u16* yb  = (u16*)(ws + ((size_t)40 << 20));  // 8 MB: y bf16 [4096][1024]
  // split-kv partial buffer overlays xb+wTa (both dead after QKV GEMM):
  // 1024 slots x 8704 B = 8.9 MB starting at ws+0
  char* pb = ws;

  cvt_bf16<<<2048, 256, 0, stream>>>(x, xb, 2 * 2048 * 1024);
  transpose_bf16<1024, 3072><<<dim3(48, 16), 256, 0, stream>>>(w_attn, wTa);
  transpose_bf16<1024, 1024><<<dim3(16, 16), 256, 0, stream>>>(w_proj, wTp);
  gemm_bt<3072, 0><<<dim3(32, 24), 256, 0, stream>>>(xb, wTa, b_attn, qb, kb, vb, nullptr);
  attn_fwd<<<dim3(32, 48), 256, 0, stream>>>(qb, kb, vb, yb, pb);
  attn_combine<<<dim3(16, 32), 256, 0, stream>>>(pb, yb);
  gemm_bt<1024, 1><<<dim3(32, 8), 256, 0, stream>>>(yb, wTp, b_proj, nullptr, nullptr, nullptr, out);
}